// Round 9
// baseline (30.939 us; speedup 1.0000x reference)
//
#include <hip/hip_runtime.h>

#define SEQ  1024
#define SEQM 1023
#define RPB  8

typedef float f32x2 __attribute__((ext_vector_type(2)));

// Packed fp32 math (VOP3P). Default modifiers = straight packed semantics.
__device__ __forceinline__ f32x2 pk_fma(f32x2 a, f32x2 b, f32x2 c) {
    f32x2 d;
    asm("v_pk_fma_f32 %0, %1, %2, %3" : "=v"(d) : "v"(a), "v"(b), "v"(c));
    return d;
}
__device__ __forceinline__ f32x2 pk_add(f32x2 a, f32x2 b) {
    f32x2 d;
    asm("v_pk_add_f32 %0, %1, %2" : "=v"(d) : "v"(a), "v"(b));
    return d;
}

// Block-wide sum reduction (wave64 shuffle + LDS across waves). Valid in t0.
__device__ __forceinline__ float block_reduce_sum(float v) {
    #pragma unroll
    for (int o = 32; o > 0; o >>= 1) v += __shfl_down(v, o, 64);
    __shared__ float s[16];
    const int lane = threadIdx.x & 63;
    const int w    = threadIdx.x >> 6;
    if (lane == 0) s[w] = v;
    __syncthreads();
    const int nw = blockDim.x >> 6;
    if (w == 0) {
        v = (lane < nw) ? s[lane] : 0.0f;
        #pragma unroll
        for (int o = 8; o > 0; o >>= 1) v += __shfl_down(v, o, 64);
    }
    return v;
}

// Compare-free rev selection (round-8, proven): candidates r_i = fma(pf,c_i,-b_i)
// plus wrap fma(pf+1024,c3,-b3); exactly one lies in [0,1); nonneg float bits
// order as u32, negatives map huge => rev = as_float(umin(bits)).
__device__ __forceinline__ float sq_elem(float valm, f32x2 pf2, float pfw,
                                         f32x2 C01, f32x2 C23,
                                         f32x2 NB01, f32x2 NB23,
                                         float c3, float nb3, float acc) {
    const f32x2 r01 = pk_fma(pf2, C01, NB01);
    const f32x2 r23 = pk_fma(pf2, C23, NB23);
    const float rw  = fmaf(pfw, c3, nb3);
    const unsigned u =
        min(min(__float_as_uint(r01.x), __float_as_uint(r01.y)),
            min(min(__float_as_uint(r23.x), __float_as_uint(r23.y)),
                __float_as_uint(rw)));
    const float rev = __uint_as_float(u);
    const float d = fmaf(__builtin_amdgcn_cosf(rev), -0.5f, valm);
    return fmaf(d, d, acc);
}

__device__ __forceinline__ float do_row(float4 v, float4 C, float4 NB,
                                        const f32x2* pf2, const float* pw,
                                        float acc) {
    f32x2 C01;  C01.x = C.x;   C01.y = C.y;
    f32x2 C23;  C23.x = C.z;   C23.y = C.w;
    f32x2 NB01; NB01.x = NB.x; NB01.y = NB.y;
    f32x2 NB23; NB23.x = NB.z; NB23.y = NB.w;
    f32x2 half2; half2.x = -0.5f; half2.y = -0.5f;
    f32x2 v01;  v01.x = v.x;   v01.y = v.y;
    f32x2 v23;  v23.x = v.z;   v23.y = v.w;
    const f32x2 vm01 = pk_add(v01, half2);
    const f32x2 vm23 = pk_add(v23, half2);
    acc = sq_elem(vm01.x, pf2[0], pw[0], C01, C23, NB01, NB23, C.w, NB.w, acc);
    acc = sq_elem(vm01.y, pf2[1], pw[1], C01, C23, NB01, NB23, C.w, NB.w, acc);
    acc = sq_elem(vm23.x, pf2[2], pw[2], C01, C23, NB01, NB23, C.w, NB.w, acc);
    acc = sq_elem(vm23.y, pf2[3], pw[3], C01, C23, NB01, NB23, C.w, NB.w, acc);
    return acc;
}

// Two-dispatch structure on purpose:
//  - round-5 lesson: per-block device-scope __threadfence = per-XCD L2
//    writeback storm (4x regression + visibility race). Never again.
//  - round-6 lesson: in-graph tiny memset node costs ~17-20us (rocclr fill
//    dispatch anomaly). No memset-based accumulator resets.
// RPB=8 / 4096 blocks (round 9): two resident generations per CU so block
// ramp/drain and stragglers overlap with the other generation's streaming.
__global__ __launch_bounds__(256) void criterion_partial(
        const float* __restrict__ outputs,
        const int*   __restrict__ indexes,
        float*       __restrict__ part,
        int B) {
    __shared__ float4 sC[RPB];
    __shared__ float4 sNB[RPB];
    __shared__ float  sW[RPB];

    const int tid  = threadIdx.x;
    const int row0 = blockIdx.x * RPB;
    const bool full = (row0 + RPB <= B);

    if (tid < RPB) {
        int r = row0 + tid;
        sW[tid] = (r < B) ? 1.0f : 0.0f;
        r = (r < B) ? r : (B - 1);
        const int4 mi = *reinterpret_cast<const int4*>(indexes + (size_t)r * 4);
        int m0 = mi.x, m1 = mi.y, m2 = mi.z, m3 = mi.w;
        int t;  // sorting network (insurance; inputs arrive sorted)
        if (m0 > m1) { t = m0; m0 = m1; m1 = t; }
        if (m2 > m3) { t = m2; m2 = m3; m3 = t; }
        if (m0 > m2) { t = m0; m0 = m2; m2 = t; }
        if (m1 > m3) { t = m1; m1 = m3; m3 = t; }
        if (m1 > m2) { t = m1; m1 = m2; m2 = t; }
        const float c0 = __builtin_amdgcn_rcpf((float)((m1 - m0) & SEQM));
        const float c1 = __builtin_amdgcn_rcpf((float)((m2 - m1) & SEQM));
        const float c2 = __builtin_amdgcn_rcpf((float)((m3 - m2) & SEQM));
        const float c3 = __builtin_amdgcn_rcpf((float)((m0 - m3) & SEQM));
        sC[tid]  = make_float4(c0, c1, c2, c3);
        sNB[tid] = make_float4(-(float)m0 * c0, -(float)m1 * c1,
                               -(float)m2 * c2, -(float)m3 * c3);
    }
    __syncthreads();

    const int   pb  = tid * 4;
    const float pf0 = (float)pb;
    f32x2 pf2[4];
    float pw[4];
    #pragma unroll
    for (int j = 0; j < 4; ++j) {
        const float pf = pf0 + (float)j;
        pf2[j].x = pf; pf2[j].y = pf;
        pw[j] = pf + 1024.0f;
    }
    float acc = 0.0f;

    if (full) {
        const float* rowp = outputs + (size_t)row0 * SEQ + pb;
        // 4-deep pipeline over 8 rows: load 4, then {load next 4, compute 4}.
        float4 a0 = *reinterpret_cast<const float4*>(rowp + 0 * SEQ);
        float4 a1 = *reinterpret_cast<const float4*>(rowp + 1 * SEQ);
        float4 a2 = *reinterpret_cast<const float4*>(rowp + 2 * SEQ);
        float4 a3 = *reinterpret_cast<const float4*>(rowp + 3 * SEQ);
        const float4 b0 = *reinterpret_cast<const float4*>(rowp + 4 * SEQ);
        const float4 b1 = *reinterpret_cast<const float4*>(rowp + 5 * SEQ);
        const float4 b2 = *reinterpret_cast<const float4*>(rowp + 6 * SEQ);
        const float4 b3 = *reinterpret_cast<const float4*>(rowp + 7 * SEQ);
        acc = do_row(a0, sC[0], sNB[0], pf2, pw, acc);
        acc = do_row(a1, sC[1], sNB[1], pf2, pw, acc);
        acc = do_row(a2, sC[2], sNB[2], pf2, pw, acc);
        acc = do_row(a3, sC[3], sNB[3], pf2, pw, acc);
        acc = do_row(b0, sC[4], sNB[4], pf2, pw, acc);
        acc = do_row(b1, sC[5], sNB[5], pf2, pw, acc);
        acc = do_row(b2, sC[6], sNB[6], pf2, pw, acc);
        acc = do_row(b3, sC[7], sNB[7], pf2, pw, acc);
    } else {
        #pragma unroll 1
        for (int rr = 0; rr < RPB; ++rr) {
            const int r = (row0 + rr < B) ? (row0 + rr) : (B - 1);
            const float4 v = *reinterpret_cast<const float4*>(
                outputs + (size_t)r * SEQ + pb);
            const float rs = do_row(v, sC[rr], sNB[rr], pf2, pw, 0.0f);
            acc = fmaf(rs, sW[rr], acc);
        }
    }

    const float bsum = block_reduce_sum(acc);
    if (tid == 0) part[blockIdx.x] = bsum;
}

// Deterministic final reduction: one block, fixed summation order.
__global__ __launch_bounds__(256) void criterion_final(
        const float* __restrict__ part,
        float*       __restrict__ out,
        int npart, float inv_bn) {
    float v = 0.0f;
    for (int i = threadIdx.x; i < npart; i += 256) v += part[i];
    const float s = block_reduce_sum(v);
    if (threadIdx.x == 0) out[0] = s * inv_bn;
}

extern "C" void kernel_launch(void* const* d_in, const int* in_sizes, int n_in,
                              void* d_out, int out_size, void* d_ws, size_t ws_size,
                              hipStream_t stream) {
    const float* outputs = (const float*)d_in[0];   // [B,1,SEQ] f32
    const int*   indexes = (const int*)d_in[1];     // [B,4] i32
    float* out  = (float*)d_out;                    // scalar
    float* part = (float*)d_ws;                     // npart floats

    const int total = in_sizes[0];                  // B * SEQ
    const int B = total / SEQ;
    const int npart = (B + RPB - 1) / RPB;          // 4096 for B=32768

    criterion_partial<<<npart, 256, 0, stream>>>(outputs, indexes, part, B);
    criterion_final<<<1, 256, 0, stream>>>(part, out, npart,
                                           (float)(1.0 / (double)total));
}

// Round 11
// 26.380 us; speedup vs baseline: 1.1728x; 1.1728x over previous
//
#include <hip/hip_runtime.h>

#define SEQ  1024
#define SEQM 1023
#define RPB  16

typedef float f32x2 __attribute__((ext_vector_type(2)));
typedef float f32x4 __attribute__((ext_vector_type(4)));

// Packed fp32 math (VOP3P). Default modifiers = straight packed semantics.
__device__ __forceinline__ f32x2 pk_fma(f32x2 a, f32x2 b, f32x2 c) {
    f32x2 d;
    asm("v_pk_fma_f32 %0, %1, %2, %3" : "=v"(d) : "v"(a), "v"(b), "v"(c));
    return d;
}
__device__ __forceinline__ f32x2 pk_add(f32x2 a, f32x2 b) {
    f32x2 d;
    asm("v_pk_add_f32 %0, %1, %2" : "=v"(d) : "v"(a), "v"(b));
    return d;
}

// Nontemporal float4 load: data is read exactly once per replay (L3 is
// thrashed by harness fills between replays), so L2 allocation is pure
// overhead; `nt` streams past it. Use native ext-vector for the builtin.
__device__ __forceinline__ float4 nt_load4(const float* p) {
    const f32x4 t = __builtin_nontemporal_load(
        reinterpret_cast<const f32x4*>(p));
    return make_float4(t.x, t.y, t.z, t.w);
}

// Block-wide sum reduction (wave64 shuffle + LDS across waves). Valid in t0.
__device__ __forceinline__ float block_reduce_sum(float v) {
    #pragma unroll
    for (int o = 32; o > 0; o >>= 1) v += __shfl_down(v, o, 64);
    __shared__ float s[16];
    const int lane = threadIdx.x & 63;
    const int w    = threadIdx.x >> 6;
    if (lane == 0) s[w] = v;
    __syncthreads();
    const int nw = blockDim.x >> 6;
    if (w == 0) {
        v = (lane < nw) ? s[lane] : 0.0f;
        #pragma unroll
        for (int o = 8; o > 0; o >>= 1) v += __shfl_down(v, o, 64);
    }
    return v;
}

// Compare-free rev selection (round-8, proven): candidates r_i = fma(pf,c_i,-b_i)
// plus wrap fma(pf+1024,c3,-b3); exactly one lies in [0,1); nonneg float bits
// order as u32, negatives map huge => rev = as_float(umin(bits)).
__device__ __forceinline__ float sq_elem(float valm, f32x2 pf2, float pfw,
                                         f32x2 C01, f32x2 C23,
                                         f32x2 NB01, f32x2 NB23,
                                         float c3, float nb3, float acc) {
    const f32x2 r01 = pk_fma(pf2, C01, NB01);
    const f32x2 r23 = pk_fma(pf2, C23, NB23);
    const float rw  = fmaf(pfw, c3, nb3);
    const unsigned u =
        min(min(__float_as_uint(r01.x), __float_as_uint(r01.y)),
            min(min(__float_as_uint(r23.x), __float_as_uint(r23.y)),
                __float_as_uint(rw)));
    const float rev = __uint_as_float(u);
    const float d = fmaf(__builtin_amdgcn_cosf(rev), -0.5f, valm);
    return fmaf(d, d, acc);
}

__device__ __forceinline__ float do_row(float4 v, float4 C, float4 NB,
                                        const f32x2* pf2, const float* pw,
                                        float acc) {
    f32x2 C01;  C01.x = C.x;   C01.y = C.y;
    f32x2 C23;  C23.x = C.z;   C23.y = C.w;
    f32x2 NB01; NB01.x = NB.x; NB01.y = NB.y;
    f32x2 NB23; NB23.x = NB.z; NB23.y = NB.w;
    f32x2 half2; half2.x = -0.5f; half2.y = -0.5f;
    f32x2 v01;  v01.x = v.x;   v01.y = v.y;
    f32x2 v23;  v23.x = v.z;   v23.y = v.w;
    const f32x2 vm01 = pk_add(v01, half2);
    const f32x2 vm23 = pk_add(v23, half2);
    acc = sq_elem(vm01.x, pf2[0], pw[0], C01, C23, NB01, NB23, C.w, NB.w, acc);
    acc = sq_elem(vm01.y, pf2[1], pw[1], C01, C23, NB01, NB23, C.w, NB.w, acc);
    acc = sq_elem(vm23.x, pf2[2], pw[2], C01, C23, NB01, NB23, C.w, NB.w, acc);
    acc = sq_elem(vm23.y, pf2[3], pw[3], C01, C23, NB01, NB23, C.w, NB.w, acc);
    return acc;
}

// Two-dispatch structure on purpose:
//  - round-5 lesson: per-block device-scope __threadfence = per-XCD L2
//    writeback storm (4x regression + visibility race). Never again.
//  - round-6 lesson: in-graph tiny memset node costs ~17-20us (rocclr fill
//    dispatch anomaly). No memset-based accumulator resets.
//  - round-9 lesson: >1 block generation per CU regresses (per-block
//    overhead doubles, no hiding gain). RPB=16 / 2048 blocks = exactly
//    full residency (8 blocks/CU) is the sweet spot.
__global__ __launch_bounds__(256) void criterion_partial(
        const float* __restrict__ outputs,
        const int*   __restrict__ indexes,
        float*       __restrict__ part,
        int B) {
    __shared__ float4 sC[RPB];
    __shared__ float4 sNB[RPB];
    __shared__ float  sW[RPB];

    const int tid  = threadIdx.x;
    const int row0 = blockIdx.x * RPB;
    const bool full = (row0 + RPB <= B);

    if (tid < RPB) {
        int r = row0 + tid;
        sW[tid] = (r < B) ? 1.0f : 0.0f;
        r = (r < B) ? r : (B - 1);
        const int4 mi = *reinterpret_cast<const int4*>(indexes + (size_t)r * 4);
        int m0 = mi.x, m1 = mi.y, m2 = mi.z, m3 = mi.w;
        int t;  // sorting network (insurance; inputs arrive sorted)
        if (m0 > m1) { t = m0; m0 = m1; m1 = t; }
        if (m2 > m3) { t = m2; m2 = m3; m3 = t; }
        if (m0 > m2) { t = m0; m0 = m2; m2 = t; }
        if (m1 > m3) { t = m1; m1 = m3; m3 = t; }
        if (m1 > m2) { t = m1; m1 = m2; m2 = t; }
        const float c0 = __builtin_amdgcn_rcpf((float)((m1 - m0) & SEQM));
        const float c1 = __builtin_amdgcn_rcpf((float)((m2 - m1) & SEQM));
        const float c2 = __builtin_amdgcn_rcpf((float)((m3 - m2) & SEQM));
        const float c3 = __builtin_amdgcn_rcpf((float)((m0 - m3) & SEQM));
        sC[tid]  = make_float4(c0, c1, c2, c3);
        sNB[tid] = make_float4(-(float)m0 * c0, -(float)m1 * c1,
                               -(float)m2 * c2, -(float)m3 * c3);
    }
    __syncthreads();

    const int   pb  = tid * 4;
    const float pf0 = (float)pb;
    f32x2 pf2[4];
    float pw[4];
    #pragma unroll
    for (int j = 0; j < 4; ++j) {
        const float pf = pf0 + (float)j;
        pf2[j].x = pf; pf2[j].y = pf;
        pw[j] = pf + 1024.0f;
    }
    float acc = 0.0f;

    if (full) {
        const float* rowp = outputs + (size_t)row0 * SEQ + pb;
        // software pipeline: next 4 rows in flight while computing current 4
        float4 a0 = nt_load4(rowp + 0 * SEQ);
        float4 a1 = nt_load4(rowp + 1 * SEQ);
        float4 a2 = nt_load4(rowp + 2 * SEQ);
        float4 a3 = nt_load4(rowp + 3 * SEQ);
        #pragma unroll 1
        for (int rr = 4; rr < RPB; rr += 4) {
            const float4 b0 = nt_load4(rowp + (rr + 0) * SEQ);
            const float4 b1 = nt_load4(rowp + (rr + 1) * SEQ);
            const float4 b2 = nt_load4(rowp + (rr + 2) * SEQ);
            const float4 b3 = nt_load4(rowp + (rr + 3) * SEQ);
            acc = do_row(a0, sC[rr - 4], sNB[rr - 4], pf2, pw, acc);
            acc = do_row(a1, sC[rr - 3], sNB[rr - 3], pf2, pw, acc);
            acc = do_row(a2, sC[rr - 2], sNB[rr - 2], pf2, pw, acc);
            acc = do_row(a3, sC[rr - 1], sNB[rr - 1], pf2, pw, acc);
            a0 = b0; a1 = b1; a2 = b2; a3 = b3;
        }
        acc = do_row(a0, sC[RPB - 4], sNB[RPB - 4], pf2, pw, acc);
        acc = do_row(a1, sC[RPB - 3], sNB[RPB - 3], pf2, pw, acc);
        acc = do_row(a2, sC[RPB - 2], sNB[RPB - 2], pf2, pw, acc);
        acc = do_row(a3, sC[RPB - 1], sNB[RPB - 1], pf2, pw, acc);
    } else {
        #pragma unroll 1
        for (int rr = 0; rr < RPB; ++rr) {
            const int r = (row0 + rr < B) ? (row0 + rr) : (B - 1);
            const float4 v = *reinterpret_cast<const float4*>(
                outputs + (size_t)r * SEQ + pb);
            const float rs = do_row(v, sC[rr], sNB[rr], pf2, pw, 0.0f);
            acc = fmaf(rs, sW[rr], acc);
        }
    }

    const float bsum = block_reduce_sum(acc);
    if (tid == 0) part[blockIdx.x] = bsum;
}

// Deterministic final reduction: one block, fixed summation order.
// npart is a multiple of 1024 here (2048): float4 reads, fixed order.
__global__ __launch_bounds__(256) void criterion_final(
        const float* __restrict__ part,
        float*       __restrict__ out,
        int npart, float inv_bn) {
    float v = 0.0f;
    for (int i = threadIdx.x * 4; i < npart; i += 1024) {
        const float4 p = *reinterpret_cast<const float4*>(part + i);
        v += (p.x + p.y) + (p.z + p.w);
    }
    const float s = block_reduce_sum(v);
    if (threadIdx.x == 0) out[0] = s * inv_bn;
}

extern "C" void kernel_launch(void* const* d_in, const int* in_sizes, int n_in,
                              void* d_out, int out_size, void* d_ws, size_t ws_size,
                              hipStream_t stream) {
    const float* outputs = (const float*)d_in[0];   // [B,1,SEQ] f32
    const int*   indexes = (const int*)d_in[1];     // [B,4] i32
    float* out  = (float*)d_out;                    // scalar
    float* part = (float*)d_ws;                     // npart floats

    const int total = in_sizes[0];                  // B * SEQ
    const int B = total / SEQ;
    const int npart = (B + RPB - 1) / RPB;          // 2048 for B=32768

    criterion_partial<<<npart, 256, 0, stream>>>(outputs, indexes, part, B);
    criterion_final<<<1, 256, 0, stream>>>(part, out, npart,
                                           (float)(1.0 / (double)total));
}